// Round 14
// baseline (564.019 us; speedup 1.0000x reference)
//
#include <hip/hip_runtime.h>
#include <hip/hip_bf16.h>
#include <cstdint>

typedef _Float16 half_t;
typedef __attribute__((ext_vector_type(8))) _Float16 half8;
typedef __attribute__((ext_vector_type(4))) _Float16 half4;
typedef __attribute__((ext_vector_type(4))) float f32x4;

#define MFMA16x32(a, b, c) __builtin_amdgcn_mfma_f32_16x16x32_f16(a, b, c, 0, 0, 0)

static constexpr int NB  = 256;   // graphs
static constexpr int NN  = 512;   // nodes per graph
static constexpr int NE  = 8192;  // edges
static constexpr int FIN = 128;
static constexpr int NH  = 256;
static constexpr int CAT = 896;

// ---------------------------------------------------------------------------
// XCD-aware bijective block swizzle (T1). Callers guarantee nwg%8==0.
// ---------------------------------------------------------------------------
__device__ __forceinline__ void xcd_swz(int& bx, int& by)
{
    const int nwg = gridDim.x * gridDim.y;
    int wgid = blockIdx.y * gridDim.x + blockIdx.x;
    wgid = (wgid & 7) * (nwg >> 3) + (wgid >> 3);
    bx = wgid % gridDim.x;
    by = wgid / gridDim.x;
}

// ---------------------------------------------------------------------------
// global_load_lds staging: 16B/lane DMA into LINEAR LDS rows of 64 halfs.
// Swizzle on GLOBAL source slot + matching un-swizzle on ds_read.
// ---------------------------------------------------------------------------
__device__ __forceinline__ void gload16(const half_t* __restrict__ g, half_t* l)
{
    __builtin_amdgcn_global_load_lds(
        (const __attribute__((address_space(1))) uint32_t*)(uintptr_t)g,
        (__attribute__((address_space(3))) uint32_t*)(uintptr_t)l, 16, 0, 0);
}

// 256-thread (4-wave) version: 128 rows x 64 halfs
__device__ __forceinline__ void stage128x64(
    const half_t* __restrict__ src, long row0, int ldk, int k0,
    half_t* lds, int tid)
{
    const int wid = tid >> 6, lane = tid & 63;
#pragma unroll
    for (int it = 0; it < 4; ++it) {
        const int rb   = wid * 32 + it * 8;
        const int row  = rb + (lane >> 3);
        const int slot = (lane & 7) ^ (row & 7);
        gload16(src + (row0 + row) * (long)ldk + k0 + slot * 8,
                lds + (size_t)rb * 64);
    }
}

__device__ __forceinline__ half8 fragr(const half_t* lds, int row, int slot)
{
    return *(const half8*)(lds + row * 64 + ((slot ^ (row & 7)) * 8));
}

// ---------------------------------------------------------------------------
// Fused per-input dtype detection + conversion
// ---------------------------------------------------------------------------
struct Tab {
    const void* src[16];
    float*      dst[16];
    int         n[16];
    int         fi[16];
    int         nseg;
};

__global__ void k_detect_all(Tab t, int* __restrict__ flags)
{
    const int s = blockIdx.x;
    if (s >= t.nseg) return;
    __shared__ int cnt_s;
    if (threadIdx.x == 0) cnt_s = 0;
    __syncthreads();
    const uint32_t* w = (const uint32_t*)t.src[s];
    int nw = t.n[s] / 2; if (nw > 2048) nw = 2048; if (nw < 1) nw = 1;
    int c = 0;
    for (int i = threadIdx.x; i < nw; i += 256) {
        const uint32_t lo = w[i] & 0xFFFFu;
        const int e = (int)((lo >> 7) & 0xFF);
        if (lo == 0u || (e >= 116 && e <= 136)) ++c;
    }
    atomicAdd(&cnt_s, c);
    __syncthreads();
    if (threadIdx.x == 0) flags[t.fi[s]] = (2 * cnt_s >= nw) ? 1 : 0;
}

__global__ void k_cvt_all(Tab t, const int* __restrict__ flags)
{
    for (int s = 0; s < t.nseg; ++s) {
        float* dst = t.dst[s];
        if (dst == nullptr) continue;
        const int is_bf = flags[t.fi[s]];
        const int n = t.n[s];
        const void* src = t.src[s];
        for (int i = blockIdx.x * 256 + threadIdx.x; i < n; i += gridDim.x * 256)
            dst[i] = is_bf
                ? __uint_as_float(((uint32_t)((const uint16_t*)src)[i]) << 16)
                : ((const float*)src)[i];
    }
}

// x -> fp16, 8 elems/thread, dual path (full batch)
__global__ void k_x2h(const void* __restrict__ xraw, half_t* __restrict__ o,
                      size_t n8, const int* __restrict__ flag)
{
    const int is_bf = *flag;
    const size_t gid0 = (size_t)blockIdx.x * blockDim.x + threadIdx.x;
    const size_t stride = (size_t)gridDim.x * blockDim.x;
    if (is_bf) {
        const uint4* src = (const uint4*)xraw;
        for (size_t i = gid0; i < n8; i += stride) {
            const uint4 v = src[i];
            half8 h;
            h[0] = (_Float16)__uint_as_float((v.x & 0xFFFFu) << 16);
            h[1] = (_Float16)__uint_as_float(v.x & 0xFFFF0000u);
            h[2] = (_Float16)__uint_as_float((v.y & 0xFFFFu) << 16);
            h[3] = (_Float16)__uint_as_float(v.y & 0xFFFF0000u);
            h[4] = (_Float16)__uint_as_float((v.z & 0xFFFFu) << 16);
            h[5] = (_Float16)__uint_as_float(v.z & 0xFFFF0000u);
            h[6] = (_Float16)__uint_as_float((v.w & 0xFFFFu) << 16);
            h[7] = (_Float16)__uint_as_float(v.w & 0xFFFF0000u);
            ((half8*)o)[i] = h;
        }
    } else {
        const float4* src = (const float4*)xraw;
        for (size_t i = gid0; i < n8; i += stride) {
            const float4 a = src[2 * i], b = src[2 * i + 1];
            half8 h;
            h[0] = (_Float16)a.x; h[1] = (_Float16)a.y;
            h[2] = (_Float16)a.z; h[3] = (_Float16)a.w;
            h[4] = (_Float16)b.x; h[5] = (_Float16)b.y;
            h[6] = (_Float16)b.z; h[7] = (_Float16)b.w;
            ((half8*)o)[i] = h;
        }
    }
}

__global__ void k_sentinel(__hip_bfloat16* __restrict__ out, float code)
{
    const int i = blockIdx.x * 256 + threadIdx.x;
    if (i < 66048) out[i] = __float2bfloat16(i < 512 ? code : 0.f);
}

__global__ void k_pick512(const float* __restrict__ a, const float* __restrict__ b,
                          float* __restrict__ f2Wc, float* __restrict__ linbsc)
{
    __shared__ float sa_s, sb_s;
    const int t = threadIdx.x;
    if (t == 0) { sa_s = 0.f; sb_s = 0.f; }
    __syncthreads();
    float va = fabsf(a[t]) + fabsf(a[t + 256]);
    float vb = fabsf(b[t]) + fabsf(b[t + 256]);
    for (int o = 32; o; o >>= 1) {
        va += __shfl_down(va, o, 64);
        vb += __shfl_down(vb, o, 64);
    }
    if ((t & 63) == 0) { atomicAdd(&sa_s, va); atomicAdd(&sb_s, vb); }
    __syncthreads();
    const float* f2 = (sa_s >= sb_s) ? a : b;
    const float* lb = (sa_s >= sb_s) ? b : a;
    f2Wc[t] = f2[t]; f2Wc[t + 256] = f2[t + 256];
    linbsc[t] = lb[t]; linbsc[t + 256] = lb[t + 256];
}

// ---------------------------------------------------------------------------
// Graph preprocessing: CSR by dst (+self loops), symmetric norm, srow.
// ---------------------------------------------------------------------------
__global__ void k_build_graph(const int* __restrict__ ei, int* __restrict__ rowptr,
                              int* __restrict__ colx, float* __restrict__ wn,
                              float* __restrict__ srow)
{
    __shared__ int   degs[NN];
    __shared__ float dinv[NN];
    __shared__ int   rp[NN + 1];
    __shared__ int   cur[NN];
    __shared__ float sacc[NN];
    __shared__ int   is64_s;
    const int t = threadIdx.x;
    degs[t] = 0; cur[t] = 0; sacc[t] = 0.f;
    if (t == 0) {
        int orv = 0;
        for (int i = 1; i < 256; i += 2) orv |= ei[i];
        is64_s = (orv == 0) ? 1 : 0;
    }
    __syncthreads();
    const bool is64 = (is64_s != 0);
    auto EV = [&](int idx) { return is64 ? ei[2 * idx] : ei[idx]; };

    for (int e = t; e < NE; e += NN)
        atomicAdd(&degs[EV(NE + e)], 1);
    __syncthreads();
    const float dv = rsqrtf(fmaxf((float)(degs[t] + 1), 1.f));
    dinv[t] = dv;
    __syncthreads();
    if (t == 0) {
        rp[0] = 0;
        for (int i = 0; i < NN; ++i) rp[i + 1] = rp[i] + degs[i] + 1;
    }
    __syncthreads();
    rowptr[t] = rp[t];
    if (t == 0) rowptr[NN] = rp[NN];
    for (int e = t; e < NE; e += NN) {
        const int s = EV(e), d = EV(NE + e);
        const int pos = atomicAdd(&cur[d], 1);
        colx[rp[d] + pos] = s;
        wn[rp[d] + pos]   = dinv[s] * dinv[d];
        atomicAdd(&sacc[d], dinv[s]);
    }
    __syncthreads();
    const int slot = rp[t + 1] - 1;
    colx[slot] = t;
    wn[slot]   = dv * dv;
    srow[t]    = dv * (sacc[t] + dv);
}

// densify CSR -> S16[512][512] fp16
__global__ void k_densify(const int* __restrict__ rowptr, const int* __restrict__ colx,
                          const float* __restrict__ wn, half_t* __restrict__ S16)
{
    __shared__ float row[NN];
    const int d = blockIdx.x;
    for (int i = threadIdx.x; i < NN; i += 256) row[i] = 0.f;
    __syncthreads();
    const int s0 = rowptr[d], s1 = rowptr[d + 1];
    for (int e = s0 + threadIdx.x; e < s1; e += 256)
        atomicAdd(&row[colx[e]], wn[e]);
    __syncthreads();
    for (int i = threadIdx.x; i < NN; i += 256)
        S16[(size_t)d * NN + i] = (half_t)row[i];
}

// ---------------------------------------------------------------------------
// Weight folding
// ---------------------------------------------------------------------------
__global__ void k_fold_wc(const float* __restrict__ lin0_W, const float* __restrict__ lin_Ws,
                          const float* __restrict__ conv_Ws,
                          half_t* __restrict__ wc0, half_t* __restrict__ wc1,
                          half_t* __restrict__ wc2)
{
    const int layer = blockIdx.y;
    const int k = blockIdx.x;
    const int n = threadIdx.x;
    const int K = (layer == 0) ? FIN : NH;
    if (k >= K) return;
    const float* lin = (layer == 0) ? lin0_W : lin_Ws + (size_t)(layer - 1) * NH * NH;
    const float* cw  = conv_Ws + (size_t)layer * NH * NH;
    float s = 0.f;
    for (int j = 0; j < NH; ++j) s += lin[k * NH + j] * cw[j * NH + n];
    half_t* o = (layer == 0) ? wc0 : ((layer == 1) ? wc1 : wc2);
    o[n * K + k] = (half_t)s;
}

// fold_wt (y=0,1: sigW/tanW transpose) + fold_vb (y=2, blocks 0..2)
__global__ void k_fold_wt(const float* __restrict__ sigW, const float* __restrict__ tanW,
                          half_t* __restrict__ sh, half_t* __restrict__ th,
                          const float* __restrict__ lin0_b, const float* __restrict__ lin_bs,
                          const float* __restrict__ conv_Ws, float* __restrict__ vb)
{
    const int which = blockIdx.y;
    if (which == 2) {
        const int layer = blockIdx.x;
        if (layer >= 3) return;
        const int n = threadIdx.x;
        const float* lb = (layer == 0) ? lin0_b : lin_bs + (size_t)(layer - 1) * NH;
        const float* cw = conv_Ws + (size_t)layer * NH * NH;
        float s = 0.f;
        for (int j = 0; j < NH; ++j) s += lb[j] * cw[j * NH + n];
        vb[layer * NH + n] = s;
        return;
    }
    const int n = blockIdx.x;
    const float* W = which ? tanW : sigW;
    half_t* o = which ? th : sh;
    for (int k = threadIdx.x; k < CAT; k += 256)
        o[(size_t)n * CAT + k] = (half_t)W[(size_t)k * NH + n];
}

// ---------------------------------------------------------------------------
// Layer GEMM with TRANSPOSED output, 2-phase dbuf gload_lds staging, BK=64.
// ---------------------------------------------------------------------------
__global__ __launch_bounds__(256, 2) void k_gemm_t(
    const half_t* __restrict__ A, const half_t* __restrict__ BT,
    half_t* __restrict__ hwT, int K)
{
    __shared__ __align__(16) half_t sm[32768];   // buf0{A,B} buf1{A,B}; lC overlay
    int bx, by; xcd_swz(bx, by);
    const int tid = threadIdx.x;
    const int lane = tid & 63, wid = tid >> 6;
    const int wr = wid >> 1, wc = wid & 1;
    const int row_l = lane & 15, kg = lane >> 4;
    const long mbase = (long)bx * 128;
    const int nbase = by * 128;
    const int nt = K >> 6;
    f32x4 acc[4][4] = {};
    stage128x64(A,  mbase, K, 0, sm, tid);
    stage128x64(BT, nbase, K, 0, sm + 8192, tid);
    __syncthreads();
    for (int kt = 0; kt < nt; ++kt) {
        half_t* cur = sm + (kt & 1) * 16384;
        if (kt + 1 < nt) {
            half_t* nxt = sm + ((kt + 1) & 1) * 16384;
            stage128x64(A,  mbase, K, (kt + 1) * 64, nxt, tid);
            stage128x64(BT, nbase, K, (kt + 1) * 64, nxt + 8192, tid);
        }
#pragma unroll
        for (int ks = 0; ks < 2; ++ks) {
            half8 af[4], bf[4];
#pragma unroll
            for (int mt = 0; mt < 4; ++mt)
                af[mt] = fragr(cur, wr * 64 + mt * 16 + row_l, ks * 4 + kg);
#pragma unroll
            for (int ntc = 0; ntc < 4; ++ntc)
                bf[ntc] = fragr(cur + 8192, wc * 64 + ntc * 16 + row_l, ks * 4 + kg);
#pragma unroll
            for (int mt = 0; mt < 4; ++mt)
#pragma unroll
                for (int ntc = 0; ntc < 4; ++ntc)
                    acc[mt][ntc] = MFMA16x32(af[mt], bf[ntc], acc[mt][ntc]);
        }
        __syncthreads();
    }
    half_t* lC = sm;
#pragma unroll
    for (int mt = 0; mt < 4; ++mt) {
        const int m_l = wr * 64 + mt * 16 + kg * 4;
#pragma unroll
        for (int ntc = 0; ntc < 4; ++ntc) {
            const int n_l = wc * 64 + ntc * 16 + row_l;
            half4 p;
            p[0] = (_Float16)acc[mt][ntc][0]; p[1] = (_Float16)acc[mt][ntc][1];
            p[2] = (_Float16)acc[mt][ntc][2]; p[3] = (_Float16)acc[mt][ntc][3];
            *(half4*)(lC + n_l * 136 + m_l) = p;
        }
    }
    __syncthreads();
    const int b  = (int)(mbase >> 9);
    const int s0 = (int)(mbase & 511);
#pragma unroll
    for (int pass = 0; pass < 8; ++pass) {
        const int n_l = pass * 16 + (tid >> 4);
        const int part = tid & 15;
        const half8 v = *(const half8*)(lC + n_l * 136 + part * 8);
        *(half8*)(hwT + ((size_t)b * 256 + nbase + n_l) * 512 + s0 + part * 8) = v;
    }
}

// ---------------------------------------------------------------------------
// Aggregation GEMM, 2-phase dbuf, BK=64, coalesced LDS-bounce epilogue.
// ---------------------------------------------------------------------------
__global__ __launch_bounds__(256, 2) void k_gemm_agg(
    const half_t* __restrict__ S16, const half_t* __restrict__ hwT,
    const float* __restrict__ srow, const float* __restrict__ vb,
    const float* __restrict__ cb, half_t* __restrict__ hout)
{
    __shared__ __align__(16) half_t sm[32768];
    int bx, by; xcd_swz(bx, by);
    const int tid = threadIdx.x;
    const int lane = tid & 63, wid = tid >> 6;
    const int wr = wid >> 1, wc = wid & 1;
    const int row_l = lane & 15, kg = lane >> 4;
    const int mbase = bx * 128;
    const int nbase = by * 128;
    f32x4 acc[4][4] = {};
    stage128x64(S16, mbase, 512, 0, sm, tid);
    stage128x64(hwT, nbase, 512, 0, sm + 8192, tid);
    __syncthreads();
    for (int kt = 0; kt < 8; ++kt) {
        half_t* cur = sm + (kt & 1) * 16384;
        if (kt + 1 < 8) {
            half_t* nxt = sm + ((kt + 1) & 1) * 16384;
            stage128x64(S16, mbase, 512, (kt + 1) * 64, nxt, tid);
            stage128x64(hwT, nbase, 512, (kt + 1) * 64, nxt + 8192, tid);
        }
#pragma unroll
        for (int ks = 0; ks < 2; ++ks) {
            half8 af[4], bf[4];
#pragma unroll
            for (int mt = 0; mt < 4; ++mt)
                af[mt] = fragr(cur, wr * 64 + mt * 16 + row_l, ks * 4 + kg);
#pragma unroll
            for (int ntc = 0; ntc < 4; ++ntc)
                bf[ntc] = fragr(cur + 8192, wc * 64 + ntc * 16 + row_l, ks * 4 + kg);
#pragma unroll
            for (int mt = 0; mt < 4; ++mt)
#pragma unroll
                for (int ntc = 0; ntc < 4; ++ntc)
                    acc[mt][ntc] = MFMA16x32(af[mt], bf[ntc], acc[mt][ntc]);
        }
        __syncthreads();
    }
    const int b  = nbase >> 8;
    const int c0 = nbase & 255;
    half_t* lC = sm;
#pragma unroll
    for (int mt = 0; mt < 4; ++mt) {
        const int m_l = wr * 64 + mt * 16 + kg * 4;
        float sr[4];
#pragma unroll
        for (int r = 0; r < 4; ++r) sr[r] = srow[mbase + m_l + r];
#pragma unroll
        for (int ntc = 0; ntc < 4; ++ntc) {
            const int n_l = wc * 64 + ntc * 16 + row_l;
            const float vbc = vb[c0 + n_l], cbc = cb[c0 + n_l];
#pragma unroll
            for (int r = 0; r < 4; ++r)
                lC[(m_l + r) * 136 + n_l] =
                    (half_t)tanhf(acc[mt][ntc][r] + sr[r] * vbc + cbc);
        }
    }
    __syncthreads();
#pragma unroll
    for (int pass = 0; pass < 8; ++pass) {
        const int row = pass * 16 + (tid >> 4);
        const int col = (tid & 15) * 8;
        const half8 v = *(const half8*)(lC + row * 136 + col);
        *(half8*)(hout + ((size_t)b * NN + mbase + row) * NH + c0 + col) = v;
    }
}

// ---------------------------------------------------------------------------
// Final GEMM (K=896): 8 waves, 256x128 tile, gload_lds staging, BK=64,
// fused sigmoid*tanh + node-pool. part[graph][tile2][256].
// ---------------------------------------------------------------------------
__global__ __launch_bounds__(512) void k_gemm_final(
    const half_t* __restrict__ x16, const half_t* __restrict__ h1,
    const half_t* __restrict__ h2, const half_t* __restrict__ h3,
    const half_t* __restrict__ bsh, const half_t* __restrict__ bth,
    const float* __restrict__ sig_b, const float* __restrict__ tan_b,
    float* __restrict__ part)
{
    __shared__ __align__(16) half_t lA[16384];    // 256 x 64
    __shared__ __align__(16) half_t lBs[8192], lBt[8192];
    __shared__ float red[4][128];
    int bx, by; xcd_swz(bx, by);
    const int tid = threadIdx.x;
    const int lane = tid & 63, wid = tid >> 6;    // wid 0..7
    const int wr = wid >> 1, wc = wid & 1;        // wr 0..3 (M), wc 0..1 (N)
    const int row_l = lane & 15, kg = lane >> 4;
    const long mbase = (long)bx * 256;
    const int sup = by;
    f32x4 aS[4][4] = {}, aT[4][4] = {};
    for (int kt = 0; kt < 14; ++kt) {
        const int k0 = kt * 64;
        const half_t* Aseg; int segK, lk;
        if (k0 < 128)      { Aseg = x16; segK = 128; lk = k0; }
        else if (k0 < 384) { Aseg = h1;  segK = 256; lk = k0 - 128; }
        else if (k0 < 640) { Aseg = h2;  segK = 256; lk = k0 - 384; }
        else               { Aseg = h3;  segK = 256; lk = k0 - 640; }
        // stage A: 256 rows, 4 issues across 8 waves
#pragma unroll
        for (int it = 0; it < 4; ++it) {
            const int rb   = it * 64 + wid * 8;
            const int row  = rb + (lane >> 3);
            const int slot = (lane & 7) ^ (row & 7);
            gload16(Aseg + (mbase + row) * (long)segK + lk + slot * 8,
                    lA + (size_t)rb * 64);
        }
        // stage Bs/Bt: 128 rows each, 2 issues
#pragma unroll
        for (int it = 0; it < 2; ++it) {
            const int rb   = it * 64 + wid * 8;
            const int row  = rb + (lane >> 3);
            const int slot = (lane & 7) ^ (row & 7);
            gload16(bsh + ((long)sup * 128 + row) * CAT + k0 + slot * 8,
                    lBs + (size_t)rb * 64);
            gload16(bth + ((long)sup * 128 + row) * CAT + k0 + slot * 8,
                    lBt + (size_t)rb * 64);
        }
        __syncthreads();
#pragma unroll
        for (int ks = 0; ks < 2; ++ks) {
            half8 af[4];
#pragma unroll
            for (int mt = 0; mt < 4; ++mt)
                af[mt] = fragr(lA, wr * 64 + mt * 16 + row_l, ks * 4 + kg);
#pragma unroll
            for (int ntc = 0; ntc < 4; ++ntc) {
                const int r = wc * 64 + ntc * 16 + row_l;
                const half8 fs = fragr(lBs, r, ks * 4 + kg);
                const half8 ft = fragr(lBt, r, ks * 4 + kg);
#pragma unroll
                for (int mt = 0; mt < 4; ++mt) {
                    aS[mt][ntc] = MFMA16x32(af[mt], fs, aS[mt][ntc]);
                    aT[mt][ntc] = MFMA16x32(af[mt], ft, aT[mt][ntc]);
                }
            }
        }
        __syncthreads();
    }
#pragma unroll
    for (int ntc = 0; ntc < 4; ++ntc) {
        const int j = sup * 128 + wc * 64 + ntc * 16 + row_l;
        const float sb = sig_b[j], tb = tan_b[j];
        float ps = 0.f;
#pragma unroll
        for (int mt = 0; mt < 4; ++mt)
#pragma unroll
            for (int r = 0; r < 4; ++r) {
                const float u = aS[mt][ntc][r] + sb;
                const float v = aT[mt][ntc][r] + tb;
                ps += (1.f / (1.f + expf(-u))) * tanhf(v);
            }
        ps += __shfl_xor(ps, 16, 64);
        ps += __shfl_xor(ps, 32, 64);
        if (lane < 16) red[wr][wc * 64 + ntc * 16 + lane] = ps;
    }
    __syncthreads();
    if (tid < 128)
        part[(size_t)(bx >> 1) * 512 + (bx & 1) * 256 + sup * 128 + tid] =
            red[0][tid] + red[1][tid] + red[2][tid] + red[3][tid];
}

// ---------------------------------------------------------------------------
// Fused: pooled -> embeds (tanh) -> head MLP -> preds. One block per graph.
// ---------------------------------------------------------------------------
__global__ __launch_bounds__(256) void k_finish(
    const float* __restrict__ part, const float* __restrict__ f1W,
    const float* __restrict__ f1b, const float* __restrict__ f2W,
    const float* __restrict__ f2b, void* __restrict__ dout,
    const int* __restrict__ flags)
{
    __shared__ float e[NH], h[NH];
    const int b = blockIdx.x, t = threadIdx.x;
    const int any = flags[0] | flags[1] | flags[2] | flags[3] | flags[4] |
                    flags[5] | flags[6];
    const int w4 = any ? 0 : 1;
    const float* p = part + (size_t)b * 512 + t;
    const float ev = tanhf(p[0] + p[256]);
    e[t] = ev;
    if (w4) ((float*)dout)[512 + b * NH + t] = ev;
    else    ((__hip_bfloat16*)dout)[512 + b * NH + t] = __float2bfloat16(ev);
    __syncthreads();
    float a = f1b[t];
    for (int k = 0; k < NH; ++k) a += e[k] * f1W[k * NH + t];
    h[t] = fmaxf(a, 0.f);
    __syncthreads();
    if (t < 64) {
        float p0 = 0.f, p1 = 0.f;
        for (int jj = t; jj < NH; jj += 64) {
            p0 += h[jj] * f2W[jj * 2 + 0];
            p1 += h[jj] * f2W[jj * 2 + 1];
        }
        for (int o = 32; o; o >>= 1) {
            p0 += __shfl_down(p0, o, 64);
            p1 += __shfl_down(p1, o, 64);
        }
        if (t == 0) {
            p0 += f2b[0]; p1 += f2b[1];
            p0 = 1.f / (1.f + expf(-p0));
            if (w4) {
                ((float*)dout)[b * 2 + 0] = p0;
                ((float*)dout)[b * 2 + 1] = p1;
            } else {
                ((__hip_bfloat16*)dout)[b * 2 + 0] = __float2bfloat16(p0);
                ((__hip_bfloat16*)dout)[b * 2 + 1] = __float2bfloat16(p1);
            }
        }
    }
}

// ---------------------------------------------------------------------------
extern "C" void kernel_launch(void* const* d_in, const int* in_sizes, int n_in,
                              void* d_out, int out_size, void* d_ws, size_t ws_size,
                              hipStream_t stream)
{
    (void)out_size;

    // ---- identify inputs by size ----
    int ix = -1, ie = -1, il0 = -1, ilw = -1, icw = -1, icb = -1, if1 = -1, if2b = -1;
    int i229[2] = {-1, -1}; int n229 = 0;
    int i512[2] = {-1, -1}; int n512 = 0;
    int i256[4] = {-1, -1, -1, -1}; int n256 = 0;
    int bad = 0;
    for (int i = 0; i < n_in && i < 16; ++i) {
        switch (in_sizes[i]) {
            case 16777216: ix = i; break;
            case 16384:    ie = i; break;
            case 32768:    il0 = i; break;
            case 131072:   ilw = i; break;
            case 196608:   icw = i; break;
            case 768:      icb = i; break;
            case 65536:    if1 = i; break;
            case 2:        if2b = i; break;
            case 229376:   if (n229 < 2) i229[n229++] = i; else bad = 1; break;
            case 512:      if (n512 < 2) i512[n512++] = i; else bad = 1; break;
            case 256:      if (n256 < 4) i256[n256++] = i; else bad = 1; break;
            default:       bad = 1; break;
        }
    }
    if (n_in != 16 || bad || ix < 0 || ie < 0 || il0 < 0 || ilw < 0 || icw < 0 ||
        icb < 0 || if1 < 0 || if2b < 0 || n229 != 2 || n512 != 2 || n256 != 4) {
        k_sentinel<<<(66048 + 255) / 256, 256, 0, stream>>>((__hip_bfloat16*)d_out, 20480.f);
        return;
    }

    char* wp = (char*)d_ws;
    auto alloc = [&](size_t sz) {
        char* p = wp;
        wp += (sz + 4095) & ~(size_t)4095;
        return p;
    };
    int*   flags  = (int*)alloc(32 * 4);
    float* c_lin0W  = (float*)alloc((size_t)FIN * NH * 4);
    float* c_linWs  = (float*)alloc((size_t)2 * NH * NH * 4);
    float* c_convWs = (float*)alloc((size_t)3 * NH * NH * 4);
    float* c_convbs = (float*)alloc((size_t)3 * NH * 4);
    float* c_sigW   = (float*)alloc((size_t)CAT * NH * 4);
    float* c_tanW   = (float*)alloc((size_t)CAT * NH * 4);
    float* c_f1W    = (float*)alloc((size_t)NH * NH * 4);
    float* c_f2b    = (float*)alloc(2 * 4);
    float* c_512a   = (float*)alloc(512 * 4);
    float* c_512b   = (float*)alloc(512 * 4);
    float* f2Wc     = (float*)alloc(512 * 4);
    float* linbsc   = (float*)alloc(512 * 4);
    float* c_b256[4];
    for (int q = 0; q < 4; ++q) c_b256[q] = (float*)alloc(256 * 4);
    int*    rowptr = (int*)alloc((NN + 1) * 4);
    int*    colx   = (int*)alloc((NE + NN) * 4);
    float*  wn     = (float*)alloc((NE + NN) * 4);
    float*  srow   = (float*)alloc(NN * 4);
    float*  vb     = (float*)alloc(3 * NH * 4);
    half_t* S16  = (half_t*)alloc((size_t)NN * NN * 2);
    half_t* wc0  = (half_t*)alloc((size_t)NH * FIN * 2);
    half_t* wc1  = (half_t*)alloc((size_t)NH * NH * 2);
    half_t* wc2  = (half_t*)alloc((size_t)NH * NH * 2);
    half_t* sgh  = (half_t*)alloc((size_t)NH * CAT * 2);
    half_t* tnh  = (half_t*)alloc((size_t)NH * CAT * 2);
    float*  part = (float*)alloc((size_t)NB * 512 * 4);         // 512 KB
    half_t* x16  = (half_t*)alloc((size_t)NB * NN * FIN * 2);   // 32 MB

    // ---- pick CBF (graphs per final chunk) and CBL (per layer chunk) ----
    const size_t fixed_end = (size_t)(wp - (char*)d_ws);
    int CBF = 256;
    int CBL;
    for (;;) {
        CBL = (CBF < 128) ? CBF : 128;
        const size_t hbytes  = 3 * (((size_t)CBF * NN * NH * 2 + 4095) & ~(size_t)4095);
        const size_t hwbytes = (((size_t)CBL * NN * NH * 2 + 4095) & ~(size_t)4095);
        if (fixed_end + hbytes + hwbytes + (1u << 20) <= ws_size || CBF <= 8) break;
        CBF >>= 1;
    }
    half_t* h1  = (half_t*)alloc((size_t)CBF * NN * NH * 2);
    half_t* h2  = (half_t*)alloc((size_t)CBF * NN * NH * 2);
    half_t* h3  = (half_t*)alloc((size_t)CBF * NN * NH * 2);
    half_t* hwT = (half_t*)alloc((size_t)CBL * NN * NH * 2);

    // ---- fused dtype detection + conversion ----
    Tab t = {};
    int s = 0;
    auto addseg = [&](int idx, float* dst, int n, int fi) {
        t.src[s] = d_in[idx]; t.dst[s] = dst; t.n[s] = n; t.fi[s] = fi; ++s;
    };
    addseg(ix,      nullptr,   16777216, 0);
    addseg(il0,     c_lin0W,   FIN * NH, 1);
    addseg(ilw,     c_linWs,   2 * NH * NH, 2);
    addseg(icw,     c_convWs,  3 * NH * NH, 3);
    addseg(i229[0], c_sigW,    CAT * NH, 4);
    addseg(i229[1], c_tanW,    CAT * NH, 5);
    addseg(if1,     c_f1W,     NH * NH, 6);
    addseg(i512[0], c_512a,    512, 7);
    addseg(i512[1], c_512b,    512, 8);
    for (int q = 0; q < 4; ++q) addseg(i256[q], c_b256[q], 256, 9 + q);
    addseg(icb,     c_convbs,  3 * NH, 13);
    addseg(if2b,    c_f2b,     2, 14);
    t.nseg = s;

    k_detect_all<<<t.nseg, 256, 0, stream>>>(t, flags);
    k_cvt_all<<<1024, 256, 0, stream>>>(t, flags);
    k_pick512<<<1, 256, 0, stream>>>(c_512a, c_512b, f2Wc, linbsc);

    const float* lin0_b = c_b256[0];
    const float* sig_b  = c_b256[1];
    const float* tan_b  = c_b256[2];
    const float* f1_b   = c_b256[3];

    k_build_graph<<<1, 512, 0, stream>>>((const int*)d_in[ie], rowptr, colx, wn, srow);
    k_densify<<<NN, 256, 0, stream>>>(rowptr, colx, wn, S16);
    k_fold_wc<<<dim3(256, 3), 256, 0, stream>>>(c_lin0W, c_linWs, c_convWs, wc0, wc1, wc2);
    k_fold_wt<<<dim3(256, 3), 256, 0, stream>>>(c_sigW, c_tanW, sgh, tnh,
                                                lin0_b, linbsc, c_convWs, vb);
    k_x2h<<<2048, 256, 0, stream>>>(d_in[ix], x16, (size_t)NB * NN * FIN / 8, flags + 0);

    const int NFC = NB / CBF;
    const int NLC = CBF / CBL;
    for (int fc = 0; fc < NFC; ++fc) {
        for (int lc = 0; lc < NLC; ++lc) {
            const size_t goff = (size_t)(fc * CBF + lc * CBL);
            half_t* x16c = x16 + goff * NN * FIN;
            const size_t hoff = (size_t)lc * CBL * NN * NH;
            k_gemm_t<<<dim3(CBL * 4, 2), 256, 0, stream>>>(x16c, wc0, hwT, 128);
            k_gemm_agg<<<dim3(4, CBL * 2), 256, 0, stream>>>(S16, hwT, srow, vb + 0,
                                                             c_convbs + 0, h1 + hoff);
            k_gemm_t<<<dim3(CBL * 4, 2), 256, 0, stream>>>(h1 + hoff, wc1, hwT, 256);
            k_gemm_agg<<<dim3(4, CBL * 2), 256, 0, stream>>>(S16, hwT, srow, vb + 256,
                                                             c_convbs + 256, h2 + hoff);
            k_gemm_t<<<dim3(CBL * 4, 2), 256, 0, stream>>>(h2 + hoff, wc2, hwT, 256);
            k_gemm_agg<<<dim3(4, CBL * 2), 256, 0, stream>>>(S16, hwT, srow, vb + 512,
                                                             c_convbs + 512, h3 + hoff);
        }
        k_gemm_final<<<dim3(CBF * 2, 2), 512, 0, stream>>>(
            x16 + (size_t)fc * CBF * NN * FIN, h1, h2, h3, sgh, tnh,
            sig_b, tan_b, part + (size_t)fc * CBF * 512);
    }
    k_finish<<<NB, 256, 0, stream>>>(part, c_f1W, f1_b, f2Wc, c_f2b, d_out, flags);
}

// Round 15
// 460.439 us; speedup vs baseline: 1.2250x; 1.2250x over previous
//
#include <hip/hip_runtime.h>
#include <hip/hip_bf16.h>
#include <cstdint>

typedef _Float16 half_t;
typedef __attribute__((ext_vector_type(8))) _Float16 half8;
typedef __attribute__((ext_vector_type(4))) _Float16 half4;
typedef __attribute__((ext_vector_type(4))) float f32x4;

#define MFMA16x32(a, b, c) __builtin_amdgcn_mfma_f32_16x16x32_f16(a, b, c, 0, 0, 0)

static constexpr int NB  = 256;   // graphs
static constexpr int NN  = 512;   // nodes per graph
static constexpr int NE  = 8192;  // edges
static constexpr int FIN = 128;
static constexpr int NH  = 256;
static constexpr int CAT = 896;

// ---------------------------------------------------------------------------
// fast transcendentals: native v_exp_f32 + v_rcp_f32 (error ~1e-6 rel,
// invisible vs bf16 output rounding and fp16 activation storage)
// ---------------------------------------------------------------------------
__device__ __forceinline__ float fsigmoid(float u)
{
    return __builtin_amdgcn_rcpf(1.f + __expf(-u));
}
__device__ __forceinline__ float ftanh(float v)
{
    const float c = fminf(fmaxf(v, -10.f), 10.f);
    const float e = __expf(2.f * c);
    return (e - 1.f) * __builtin_amdgcn_rcpf(e + 1.f);
}

// ---------------------------------------------------------------------------
// XCD-aware bijective block swizzle (T1). Callers guarantee nwg%8==0.
// ---------------------------------------------------------------------------
__device__ __forceinline__ void xcd_swz(int& bx, int& by)
{
    const int nwg = gridDim.x * gridDim.y;
    int wgid = blockIdx.y * gridDim.x + blockIdx.x;
    wgid = (wgid & 7) * (nwg >> 3) + (wgid >> 3);
    bx = wgid % gridDim.x;
    by = wgid / gridDim.x;
}

// ---------------------------------------------------------------------------
// global_load_lds staging: 16B/lane DMA into LINEAR LDS rows of 64 halfs.
// Swizzle on GLOBAL source slot + matching un-swizzle on ds_read.
// ---------------------------------------------------------------------------
__device__ __forceinline__ void gload16(const half_t* __restrict__ g, half_t* l)
{
    __builtin_amdgcn_global_load_lds(
        (const __attribute__((address_space(1))) uint32_t*)(uintptr_t)g,
        (__attribute__((address_space(3))) uint32_t*)(uintptr_t)l, 16, 0, 0);
}

__device__ __forceinline__ void stage128x64(
    const half_t* __restrict__ src, long row0, int ldk, int k0,
    half_t* lds, int tid)
{
    const int wid = tid >> 6, lane = tid & 63;
#pragma unroll
    for (int it = 0; it < 4; ++it) {
        const int rb   = wid * 32 + it * 8;
        const int row  = rb + (lane >> 3);
        const int slot = (lane & 7) ^ (row & 7);
        gload16(src + (row0 + row) * (long)ldk + k0 + slot * 8,
                lds + (size_t)rb * 64);
    }
}

__device__ __forceinline__ half8 fragr(const half_t* lds, int row, int slot)
{
    return *(const half8*)(lds + row * 64 + ((slot ^ (row & 7)) * 8));
}

// ---------------------------------------------------------------------------
// Fused per-input dtype detection + conversion
// ---------------------------------------------------------------------------
struct Tab {
    const void* src[16];
    float*      dst[16];
    int         n[16];
    int         fi[16];
    int         nseg;
};

__global__ void k_detect_all(Tab t, int* __restrict__ flags)
{
    const int s = blockIdx.x;
    if (s >= t.nseg) return;
    __shared__ int cnt_s;
    if (threadIdx.x == 0) cnt_s = 0;
    __syncthreads();
    const uint32_t* w = (const uint32_t*)t.src[s];
    int nw = t.n[s] / 2; if (nw > 2048) nw = 2048; if (nw < 1) nw = 1;
    int c = 0;
    for (int i = threadIdx.x; i < nw; i += 256) {
        const uint32_t lo = w[i] & 0xFFFFu;
        const int e = (int)((lo >> 7) & 0xFF);
        if (lo == 0u || (e >= 116 && e <= 136)) ++c;
    }
    atomicAdd(&cnt_s, c);
    __syncthreads();
    if (threadIdx.x == 0) flags[t.fi[s]] = (2 * cnt_s >= nw) ? 1 : 0;
}

__global__ void k_cvt_all(Tab t, const int* __restrict__ flags)
{
    for (int s = 0; s < t.nseg; ++s) {
        float* dst = t.dst[s];
        if (dst == nullptr) continue;
        const int is_bf = flags[t.fi[s]];
        const int n = t.n[s];
        const void* src = t.src[s];
        for (int i = blockIdx.x * 256 + threadIdx.x; i < n; i += gridDim.x * 256)
            dst[i] = is_bf
                ? __uint_as_float(((uint32_t)((const uint16_t*)src)[i]) << 16)
                : ((const float*)src)[i];
    }
}

// x -> fp16, 8 elems/thread, dual path (full batch)
__global__ void k_x2h(const void* __restrict__ xraw, half_t* __restrict__ o,
                      size_t n8, const int* __restrict__ flag)
{
    const int is_bf = *flag;
    const size_t gid0 = (size_t)blockIdx.x * blockDim.x + threadIdx.x;
    const size_t stride = (size_t)gridDim.x * blockDim.x;
    if (is_bf) {
        const uint4* src = (const uint4*)xraw;
        for (size_t i = gid0; i < n8; i += stride) {
            const uint4 v = src[i];
            half8 h;
            h[0] = (_Float16)__uint_as_float((v.x & 0xFFFFu) << 16);
            h[1] = (_Float16)__uint_as_float(v.x & 0xFFFF0000u);
            h[2] = (_Float16)__uint_as_float((v.y & 0xFFFFu) << 16);
            h[3] = (_Float16)__uint_as_float(v.y & 0xFFFF0000u);
            h[4] = (_Float16)__uint_as_float((v.z & 0xFFFFu) << 16);
            h[5] = (_Float16)__uint_as_float(v.z & 0xFFFF0000u);
            h[6] = (_Float16)__uint_as_float((v.w & 0xFFFFu) << 16);
            h[7] = (_Float16)__uint_as_float(v.w & 0xFFFF0000u);
            ((half8*)o)[i] = h;
        }
    } else {
        const float4* src = (const float4*)xraw;
        for (size_t i = gid0; i < n8; i += stride) {
            const float4 a = src[2 * i], b = src[2 * i + 1];
            half8 h;
            h[0] = (_Float16)a.x; h[1] = (_Float16)a.y;
            h[2] = (_Float16)a.z; h[3] = (_Float16)a.w;
            h[4] = (_Float16)b.x; h[5] = (_Float16)b.y;
            h[6] = (_Float16)b.z; h[7] = (_Float16)b.w;
            ((half8*)o)[i] = h;
        }
    }
}

__global__ void k_sentinel(__hip_bfloat16* __restrict__ out, float code)
{
    const int i = blockIdx.x * 256 + threadIdx.x;
    if (i < 66048) out[i] = __float2bfloat16(i < 512 ? code : 0.f);
}

__global__ void k_pick512(const float* __restrict__ a, const float* __restrict__ b,
                          float* __restrict__ f2Wc, float* __restrict__ linbsc)
{
    __shared__ float sa_s, sb_s;
    const int t = threadIdx.x;
    if (t == 0) { sa_s = 0.f; sb_s = 0.f; }
    __syncthreads();
    float va = fabsf(a[t]) + fabsf(a[t + 256]);
    float vb = fabsf(b[t]) + fabsf(b[t + 256]);
    for (int o = 32; o; o >>= 1) {
        va += __shfl_down(va, o, 64);
        vb += __shfl_down(vb, o, 64);
    }
    if ((t & 63) == 0) { atomicAdd(&sa_s, va); atomicAdd(&sb_s, vb); }
    __syncthreads();
    const float* f2 = (sa_s >= sb_s) ? a : b;
    const float* lb = (sa_s >= sb_s) ? b : a;
    f2Wc[t] = f2[t]; f2Wc[t + 256] = f2[t + 256];
    linbsc[t] = lb[t]; linbsc[t + 256] = lb[t + 256];
}

// ---------------------------------------------------------------------------
// Graph preprocessing: CSR by dst (+self loops), symmetric norm, srow.
// ---------------------------------------------------------------------------
__global__ void k_build_graph(const int* __restrict__ ei, int* __restrict__ rowptr,
                              int* __restrict__ colx, float* __restrict__ wn,
                              float* __restrict__ srow)
{
    __shared__ int   degs[NN];
    __shared__ float dinv[NN];
    __shared__ int   rp[NN + 1];
    __shared__ int   cur[NN];
    __shared__ float sacc[NN];
    __shared__ int   is64_s;
    const int t = threadIdx.x;
    degs[t] = 0; cur[t] = 0; sacc[t] = 0.f;
    if (t == 0) {
        int orv = 0;
        for (int i = 1; i < 256; i += 2) orv |= ei[i];
        is64_s = (orv == 0) ? 1 : 0;
    }
    __syncthreads();
    const bool is64 = (is64_s != 0);
    auto EV = [&](int idx) { return is64 ? ei[2 * idx] : ei[idx]; };

    for (int e = t; e < NE; e += NN)
        atomicAdd(&degs[EV(NE + e)], 1);
    __syncthreads();
    const float dv = rsqrtf(fmaxf((float)(degs[t] + 1), 1.f));
    dinv[t] = dv;
    __syncthreads();
    if (t == 0) {
        rp[0] = 0;
        for (int i = 0; i < NN; ++i) rp[i + 1] = rp[i] + degs[i] + 1;
    }
    __syncthreads();
    rowptr[t] = rp[t];
    if (t == 0) rowptr[NN] = rp[NN];
    for (int e = t; e < NE; e += NN) {
        const int s = EV(e), d = EV(NE + e);
        const int pos = atomicAdd(&cur[d], 1);
        colx[rp[d] + pos] = s;
        wn[rp[d] + pos]   = dinv[s] * dinv[d];
        atomicAdd(&sacc[d], dinv[s]);
    }
    __syncthreads();
    const int slot = rp[t + 1] - 1;
    colx[slot] = t;
    wn[slot]   = dv * dv;
    srow[t]    = dv * (sacc[t] + dv);
}

// densify CSR -> S16[512][512] fp16
__global__ void k_densify(const int* __restrict__ rowptr, const int* __restrict__ colx,
                          const float* __restrict__ wn, half_t* __restrict__ S16)
{
    __shared__ float row[NN];
    const int d = blockIdx.x;
    for (int i = threadIdx.x; i < NN; i += 256) row[i] = 0.f;
    __syncthreads();
    const int s0 = rowptr[d], s1 = rowptr[d + 1];
    for (int e = s0 + threadIdx.x; e < s1; e += 256)
        atomicAdd(&row[colx[e]], wn[e]);
    __syncthreads();
    for (int i = threadIdx.x; i < NN; i += 256)
        S16[(size_t)d * NN + i] = (half_t)row[i];
}

// ---------------------------------------------------------------------------
// Weight folding
// ---------------------------------------------------------------------------
__global__ void k_fold_wc(const float* __restrict__ lin0_W, const float* __restrict__ lin_Ws,
                          const float* __restrict__ conv_Ws,
                          half_t* __restrict__ wc0, half_t* __restrict__ wc1,
                          half_t* __restrict__ wc2)
{
    const int layer = blockIdx.y;
    const int k = blockIdx.x;
    const int n = threadIdx.x;
    const int K = (layer == 0) ? FIN : NH;
    if (k >= K) return;
    const float* lin = (layer == 0) ? lin0_W : lin_Ws + (size_t)(layer - 1) * NH * NH;
    const float* cw  = conv_Ws + (size_t)layer * NH * NH;
    float s = 0.f;
    for (int j = 0; j < NH; ++j) s += lin[k * NH + j] * cw[j * NH + n];
    half_t* o = (layer == 0) ? wc0 : ((layer == 1) ? wc1 : wc2);
    o[n * K + k] = (half_t)s;
}

// fold_wt (y=0,1: sigW/tanW transpose) + fold_vb (y=2, blocks 0..2)
__global__ void k_fold_wt(const float* __restrict__ sigW, const float* __restrict__ tanW,
                          half_t* __restrict__ sh, half_t* __restrict__ th,
                          const float* __restrict__ lin0_b, const float* __restrict__ lin_bs,
                          const float* __restrict__ conv_Ws, float* __restrict__ vb)
{
    const int which = blockIdx.y;
    if (which == 2) {
        const int layer = blockIdx.x;
        if (layer >= 3) return;
        const int n = threadIdx.x;
        const float* lb = (layer == 0) ? lin0_b : lin_bs + (size_t)(layer - 1) * NH;
        const float* cw = conv_Ws + (size_t)layer * NH * NH;
        float s = 0.f;
        for (int j = 0; j < NH; ++j) s += lb[j] * cw[j * NH + n];
        vb[layer * NH + n] = s;
        return;
    }
    const int n = blockIdx.x;
    const float* W = which ? tanW : sigW;
    half_t* o = which ? th : sh;
    for (int k = threadIdx.x; k < CAT; k += 256)
        o[(size_t)n * CAT + k] = (half_t)W[(size_t)k * NH + n];
}

// ---------------------------------------------------------------------------
// Layer GEMM with TRANSPOSED output, gload_lds staging, BK=64. XCD-swizzled.
// (R13-proven single-buffer structure)
// ---------------------------------------------------------------------------
__global__ __launch_bounds__(256, 2) void k_gemm_t(
    const half_t* __restrict__ A, const half_t* __restrict__ BT,
    half_t* __restrict__ hwT, int K)
{
    __shared__ __align__(16) half_t sm[17408];   // lA|lB; reused as lC
    half_t* lA = sm;
    half_t* lB = sm + 8192;
    int bx, by; xcd_swz(bx, by);
    const int tid = threadIdx.x;
    const int lane = tid & 63, wid = tid >> 6;
    const int wr = wid >> 1, wc = wid & 1;
    const int row_l = lane & 15, kg = lane >> 4;
    const long mbase = (long)bx * 128;
    const int nbase = by * 128;
    f32x4 acc[4][4] = {};
    for (int k0 = 0; k0 < K; k0 += 64) {
        stage128x64(A,  mbase, K, k0, lA, tid);
        stage128x64(BT, nbase, K, k0, lB, tid);
        __syncthreads();
#pragma unroll
        for (int ks = 0; ks < 2; ++ks) {
            half8 af[4], bf[4];
#pragma unroll
            for (int mt = 0; mt < 4; ++mt)
                af[mt] = fragr(lA, wr * 64 + mt * 16 + row_l, ks * 4 + kg);
#pragma unroll
            for (int nt = 0; nt < 4; ++nt)
                bf[nt] = fragr(lB, wc * 64 + nt * 16 + row_l, ks * 4 + kg);
#pragma unroll
            for (int mt = 0; mt < 4; ++mt)
#pragma unroll
                for (int nt = 0; nt < 4; ++nt)
                    acc[mt][nt] = MFMA16x32(af[mt], bf[nt], acc[mt][nt]);
        }
        __syncthreads();
    }
    half_t* lC = sm;
#pragma unroll
    for (int mt = 0; mt < 4; ++mt) {
        const int m_l = wr * 64 + mt * 16 + kg * 4;
#pragma unroll
        for (int nt = 0; nt < 4; ++nt) {
            const int n_l = wc * 64 + nt * 16 + row_l;
            half4 p;
            p[0] = (_Float16)acc[mt][nt][0]; p[1] = (_Float16)acc[mt][nt][1];
            p[2] = (_Float16)acc[mt][nt][2]; p[3] = (_Float16)acc[mt][nt][3];
            *(half4*)(lC + n_l * 136 + m_l) = p;
        }
    }
    __syncthreads();
    const int b  = (int)(mbase >> 9);
    const int s0 = (int)(mbase & 511);
#pragma unroll
    for (int pass = 0; pass < 8; ++pass) {
        const int n_l = pass * 16 + (tid >> 4);
        const int part = tid & 15;
        const half8 v = *(const half8*)(lC + n_l * 136 + part * 8);
        *(half8*)(hwT + ((size_t)b * 256 + nbase + n_l) * 512 + s0 + part * 8) = v;
    }
}

// ---------------------------------------------------------------------------
// Aggregation GEMM, gload_lds staging, BK=64, coalesced epilogue. XCD-swizzled.
// (R13-proven single-buffer structure; fast tanh in epilogue)
// ---------------------------------------------------------------------------
__global__ __launch_bounds__(256, 2) void k_gemm_agg(
    const half_t* __restrict__ S16, const half_t* __restrict__ hwT,
    const float* __restrict__ srow, const float* __restrict__ vb,
    const float* __restrict__ cb, half_t* __restrict__ hout)
{
    __shared__ __align__(16) half_t sm[17408];   // lA|lB; reused as lC[m][136]
    half_t* lA = sm;
    half_t* lB = sm + 8192;
    int bx, by; xcd_swz(bx, by);
    const int tid = threadIdx.x;
    const int lane = tid & 63, wid = tid >> 6;
    const int wr = wid >> 1, wc = wid & 1;
    const int row_l = lane & 15, kg = lane >> 4;
    const int mbase = bx * 128;
    const int nbase = by * 128;
    f32x4 acc[4][4] = {};
    for (int k0 = 0; k0 < 512; k0 += 64) {
        stage128x64(S16, mbase, 512, k0, lA, tid);
        stage128x64(hwT, nbase, 512, k0, lB, tid);
        __syncthreads();
#pragma unroll
        for (int ks = 0; ks < 2; ++ks) {
            half8 af[4], bf[4];
#pragma unroll
            for (int mt = 0; mt < 4; ++mt)
                af[mt] = fragr(lA, wr * 64 + mt * 16 + row_l, ks * 4 + kg);
#pragma unroll
            for (int nt = 0; nt < 4; ++nt)
                bf[nt] = fragr(lB, wc * 64 + nt * 16 + row_l, ks * 4 + kg);
#pragma unroll
            for (int mt = 0; mt < 4; ++mt)
#pragma unroll
                for (int nt = 0; nt < 4; ++nt)
                    acc[mt][nt] = MFMA16x32(af[mt], bf[nt], acc[mt][nt]);
        }
        __syncthreads();
    }
    const int b  = nbase >> 8;
    const int c0 = nbase & 255;
    half_t* lC = sm;
#pragma unroll
    for (int mt = 0; mt < 4; ++mt) {
        const int m_l = wr * 64 + mt * 16 + kg * 4;
        float sr[4];
#pragma unroll
        for (int r = 0; r < 4; ++r) sr[r] = srow[mbase + m_l + r];
#pragma unroll
        for (int nt = 0; nt < 4; ++nt) {
            const int n_l = wc * 64 + nt * 16 + row_l;
            const float vbc = vb[c0 + n_l], cbc = cb[c0 + n_l];
#pragma unroll
            for (int r = 0; r < 4; ++r)
                lC[(m_l + r) * 136 + n_l] =
                    (half_t)ftanh(acc[mt][nt][r] + sr[r] * vbc + cbc);
        }
    }
    __syncthreads();
#pragma unroll
    for (int pass = 0; pass < 8; ++pass) {
        const int row = pass * 16 + (tid >> 4);
        const int col = (tid & 15) * 8;
        const half8 v = *(const half8*)(lC + row * 136 + col);
        *(half8*)(hout + ((size_t)b * NN + mbase + row) * NH + c0 + col) = v;
    }
}

// ---------------------------------------------------------------------------
// Final GEMM (K=896), gload_lds staging, BK=64, fused fast-sigmoid*tanh + pool.
// XCD-swizzled. (R13-proven 4-wave 128x128 structure)
// ---------------------------------------------------------------------------
__global__ __launch_bounds__(256, 2) void k_gemm_final(
    const half_t* __restrict__ x16, const half_t* __restrict__ h1,
    const half_t* __restrict__ h2, const half_t* __restrict__ h3,
    const half_t* __restrict__ bsh, const half_t* __restrict__ bth,
    const float* __restrict__ sig_b, const float* __restrict__ tan_b,
    float* __restrict__ part)
{
    __shared__ __align__(16) half_t sm[24576];   // lA | lBs | lBt
    __shared__ float red[2][128];
    half_t* lA  = sm;
    half_t* lBs = sm + 8192;
    half_t* lBt = sm + 16384;
    int bx, by; xcd_swz(bx, by);
    const int tid = threadIdx.x;
    const int lane = tid & 63, wid = tid >> 6;
    const int wr = wid >> 1, wc = wid & 1;
    const int row_l = lane & 15, kg = lane >> 4;
    const long mbase = (long)bx * 128;
    const int sup = by;
    f32x4 aS[4][4] = {}, aT[4][4] = {};
    for (int kt = 0; kt < 14; ++kt) {
        const int k0 = kt * 64;
        const half_t* Aseg; int segK, lk;
        if (k0 < 128)      { Aseg = x16; segK = 128; lk = k0; }
        else if (k0 < 384) { Aseg = h1;  segK = 256; lk = k0 - 128; }
        else if (k0 < 640) { Aseg = h2;  segK = 256; lk = k0 - 384; }
        else               { Aseg = h3;  segK = 256; lk = k0 - 640; }
        stage128x64(Aseg, mbase, segK, lk, lA, tid);
        stage128x64(bsh, (long)sup * 128, CAT, k0, lBs, tid);
        stage128x64(bth, (long)sup * 128, CAT, k0, lBt, tid);
        __syncthreads();
#pragma unroll
        for (int ks = 0; ks < 2; ++ks) {
            half8 af[4];
#pragma unroll
            for (int mt = 0; mt < 4; ++mt)
                af[mt] = fragr(lA, wr * 64 + mt * 16 + row_l, ks * 4 + kg);
#pragma unroll
            for (int nt = 0; nt < 4; ++nt) {
                const int r = wc * 64 + nt * 16 + row_l;
                const half8 fs = fragr(lBs, r, ks * 4 + kg);
                const half8 ft = fragr(lBt, r, ks * 4 + kg);
#pragma unroll
                for (int mt = 0; mt < 4; ++mt) {
                    aS[mt][nt] = MFMA16x32(af[mt], fs, aS[mt][nt]);
                    aT[mt][nt] = MFMA16x32(af[mt], ft, aT[mt][nt]);
                }
            }
        }
        __syncthreads();
    }
#pragma unroll
    for (int nt = 0; nt < 4; ++nt) {
        const int j = sup * 128 + wc * 64 + nt * 16 + row_l;
        const float sb = sig_b[j], tb = tan_b[j];
        float ps = 0.f;
#pragma unroll
        for (int mt = 0; mt < 4; ++mt)
#pragma unroll
            for (int r = 0; r < 4; ++r) {
                const float u = aS[mt][nt][r] + sb;
                const float v = aT[mt][nt][r] + tb;
                ps += fsigmoid(u) * ftanh(v);
            }
        ps += __shfl_xor(ps, 16, 64);
        ps += __shfl_xor(ps, 32, 64);
        if (lane < 16) red[wr][wc * 64 + nt * 16 + lane] = ps;
    }
    __syncthreads();
    if (tid < 128)
        part[(long)bx * 256 + sup * 128 + tid] = red[0][tid] + red[1][tid];
}

// ---------------------------------------------------------------------------
// Fused: pooled -> embeds (tanh) -> head MLP -> preds. One block per graph.
// ---------------------------------------------------------------------------
__global__ __launch_bounds__(256) void k_finish(
    const float* __restrict__ part, const float* __restrict__ f1W,
    const float* __restrict__ f1b, const float* __restrict__ f2W,
    const float* __restrict__ f2b, void* __restrict__ dout,
    const int* __restrict__ flags)
{
    __shared__ float e[NH], h[NH];
    const int b = blockIdx.x, t = threadIdx.x;
    const int any = flags[0] | flags[1] | flags[2] | flags[3] | flags[4] |
                    flags[5] | flags[6];
    const int w4 = any ? 0 : 1;
    const float* p = part + (size_t)b * 1024 + t;
    const float ev = tanhf(p[0] + p[256] + p[512] + p[768]);
    e[t] = ev;
    if (w4) ((float*)dout)[512 + b * NH + t] = ev;
    else    ((__hip_bfloat16*)dout)[512 + b * NH + t] = __float2bfloat16(ev);
    __syncthreads();
    float a = f1b[t];
    for (int k = 0; k < NH; ++k) a += e[k] * f1W[k * NH + t];
    h[t] = fmaxf(a, 0.f);
    __syncthreads();
    if (t < 64) {
        float p0 = 0.f, p1 = 0.f;
        for (int jj = t; jj < NH; jj += 64) {
            p0 += h[jj] * f2W[jj * 2 + 0];
            p1 += h[jj] * f2W[jj * 2 + 1];
        }
        for (int o = 32; o; o >>= 1) {
            p0 += __shfl_down(p0, o, 64);
            p1 += __shfl_down(p1, o, 64);
        }
        if (t == 0) {
            p0 += f2b[0]; p1 += f2b[1];
            p0 = 1.f / (1.f + expf(-p0));
            if (w4) {
                ((float*)dout)[b * 2 + 0] = p0;
                ((float*)dout)[b * 2 + 1] = p1;
            } else {
                ((__hip_bfloat16*)dout)[b * 2 + 0] = __float2bfloat16(p0);
                ((__hip_bfloat16*)dout)[b * 2 + 1] = __float2bfloat16(p1);
            }
        }
    }
}

// ---------------------------------------------------------------------------
extern "C" void kernel_launch(void* const* d_in, const int* in_sizes, int n_in,
                              void* d_out, int out_size, void* d_ws, size_t ws_size,
                              hipStream_t stream)
{
    (void)out_size;

    // ---- identify inputs by size ----
    int ix = -1, ie = -1, il0 = -1, ilw = -1, icw = -1, icb = -1, if1 = -1, if2b = -1;
    int i229[2] = {-1, -1}; int n229 = 0;
    int i512[2] = {-1, -1}; int n512 = 0;
    int i256[4] = {-1, -1, -1, -1}; int n256 = 0;
    int bad = 0;
    for (int i = 0; i < n_in && i < 16; ++i) {
        switch (in_sizes[i]) {
            case 16777216: ix = i; break;
            case 16384:    ie = i; break;
            case 32768:    il0 = i; break;
            case 131072:   ilw = i; break;
            case 196608:   icw = i; break;
            case 768:      icb = i; break;
            case 65536:    if1 = i; break;
            case 2:        if2b = i; break;
            case 229376:   if (n229 < 2) i229[n229++] = i; else bad = 1; break;
            case 512:      if (n512 < 2) i512[n512++] = i; else bad = 1; break;
            case 256:      if (n256 < 4) i256[n256++] = i; else bad = 1; break;
            default:       bad = 1; break;
        }
    }
    if (n_in != 16 || bad || ix < 0 || ie < 0 || il0 < 0 || ilw < 0 || icw < 0 ||
        icb < 0 || if1 < 0 || if2b < 0 || n229 != 2 || n512 != 2 || n256 != 4) {
        k_sentinel<<<(66048 + 255) / 256, 256, 0, stream>>>((__hip_bfloat16*)d_out, 20480.f);
        return;
    }

    char* wp = (char*)d_ws;
    auto alloc = [&](size_t sz) {
        char* p = wp;
        wp += (sz + 4095) & ~(size_t)4095;
        return p;
    };
    int*   flags  = (int*)alloc(32 * 4);
    float* c_lin0W  = (float*)alloc((size_t)FIN * NH * 4);
    float* c_linWs  = (float*)alloc((size_t)2 * NH * NH * 4);
    float* c_convWs = (float*)alloc((size_t)3 * NH * NH * 4);
    float* c_convbs = (float*)alloc((size_t)3 * NH * 4);
    float* c_sigW   = (float*)alloc((size_t)CAT * NH * 4);
    float* c_tanW   = (float*)alloc((size_t)CAT * NH * 4);
    float* c_f1W    = (float*)alloc((size_t)NH * NH * 4);
    float* c_f2b    = (float*)alloc(2 * 4);
    float* c_512a   = (float*)alloc(512 * 4);
    float* c_512b   = (float*)alloc(512 * 4);
    float* f2Wc     = (float*)alloc(512 * 4);
    float* linbsc   = (float*)alloc(512 * 4);
    float* c_b256[4];
    for (int q = 0; q < 4; ++q) c_b256[q] = (float*)alloc(256 * 4);
    int*    rowptr = (int*)alloc((NN + 1) * 4);
    int*    colx   = (int*)alloc((NE + NN) * 4);
    float*  wn     = (float*)alloc((NE + NN) * 4);
    float*  srow   = (float*)alloc(NN * 4);
    float*  vb     = (float*)alloc(3 * NH * 4);
    half_t* S16  = (half_t*)alloc((size_t)NN * NN * 2);
    half_t* wc0  = (half_t*)alloc((size_t)NH * FIN * 2);
    half_t* wc1  = (half_t*)alloc((size_t)NH * NH * 2);
    half_t* wc2  = (half_t*)alloc((size_t)NH * NH * 2);
    half_t* sgh  = (half_t*)alloc((size_t)NH * CAT * 2);
    half_t* tnh  = (half_t*)alloc((size_t)NH * CAT * 2);
    float*  part = (float*)alloc((size_t)1024 * 256 * 4);
    half_t* x16  = (half_t*)alloc((size_t)NB * NN * FIN * 2);   // 32 MB full batch

    // ---- pick chunk size CB (up to full batch) for h1..h3 + hwT ----
    const size_t fixed_end = (size_t)(wp - (char*)d_ws);
    int CB = 256;
    while (CB > 4) {
        const size_t mc = (size_t)CB * NN;
        const size_t act = 4 * ((mc * NH * 2 + 4095) & ~(size_t)4095);
        if (fixed_end + act + (1u << 20) <= ws_size) break;
        CB >>= 1;
    }
    const size_t MC = (size_t)CB * NN;
    const int NCH = NB / CB;

    half_t* h1c  = (half_t*)alloc(MC * NH * 2);
    half_t* h2c  = (half_t*)alloc(MC * NH * 2);
    half_t* h3c  = (half_t*)alloc(MC * NH * 2);
    half_t* hwT  = (half_t*)alloc(MC * NH * 2);

    // ---- fused dtype detection + conversion ----
    Tab t = {};
    int s = 0;
    auto addseg = [&](int idx, float* dst, int n, int fi) {
        t.src[s] = d_in[idx]; t.dst[s] = dst; t.n[s] = n; t.fi[s] = fi; ++s;
    };
    addseg(ix,      nullptr,   16777216, 0);
    addseg(il0,     c_lin0W,   FIN * NH, 1);
    addseg(ilw,     c_linWs,   2 * NH * NH, 2);
    addseg(icw,     c_convWs,  3 * NH * NH, 3);
    addseg(i229[0], c_sigW,    CAT * NH, 4);
    addseg(i229[1], c_tanW,    CAT * NH, 5);
    addseg(if1,     c_f1W,     NH * NH, 6);
    addseg(i512[0], c_512a,    512, 7);
    addseg(i512[1], c_512b,    512, 8);
    for (int q = 0; q < 4; ++q) addseg(i256[q], c_b256[q], 256, 9 + q);
    addseg(icb,     c_convbs,  3 * NH, 13);
    addseg(if2b,    c_f2b,     2, 14);
    t.nseg = s;

    k_detect_all<<<t.nseg, 256, 0, stream>>>(t, flags);
    k_cvt_all<<<1024, 256, 0, stream>>>(t, flags);
    k_pick512<<<1, 256, 0, stream>>>(c_512a, c_512b, f2Wc, linbsc);

    const float* lin0_b = c_b256[0];
    const float* sig_b  = c_b256[1];
    const float* tan_b  = c_b256[2];
    const float* f1_b   = c_b256[3];

    k_build_graph<<<1, 512, 0, stream>>>((const int*)d_in[ie], rowptr, colx, wn, srow);
    k_densify<<<NN, 256, 0, stream>>>(rowptr, colx, wn, S16);
    k_fold_wc<<<dim3(256, 3), 256, 0, stream>>>(c_lin0W, c_linWs, c_convWs, wc0, wc1, wc2);
    k_fold_wt<<<dim3(256, 3), 256, 0, stream>>>(c_sigW, c_tanW, sgh, tnh,
                                                lin0_b, linbsc, c_convWs, vb);
    k_x2h<<<2048, 256, 0, stream>>>(d_in[ix], x16, (size_t)NB * NN * FIN / 8, flags + 0);

    for (int c = 0; c < NCH; ++c) {
        half_t* x16c = x16 + (size_t)c * MC * FIN;
        k_gemm_t<<<dim3(CB * 4, 2), 256, 0, stream>>>(x16c, wc0, hwT, 128);
        k_gemm_agg<<<dim3(4, CB * 2), 256, 0, stream>>>(S16, hwT, srow, vb + 0,
                                                        c_convbs + 0, h1c);
        k_gemm_t<<<dim3(CB * 4, 2), 256, 0, stream>>>(h1c, wc1, hwT, 256);
        k_gemm_agg<<<dim3(4, CB * 2), 256, 0, stream>>>(S16, hwT, srow, vb + 256,
                                                        c_convbs + 256, h2c);
        k_gemm_t<<<dim3(CB * 4, 2), 256, 0, stream>>>(h2c, wc2, hwT, 256);
        k_gemm_agg<<<dim3(4, CB * 2), 256, 0, stream>>>(S16, hwT, srow, vb + 512,
                                                        c_convbs + 512, h3c);
        k_gemm_final<<<dim3(CB * 4, 2), 256, 0, stream>>>(
            x16c, h1c, h2c, h3c, sgh, tnh, sig_b, tan_b,
            part + (size_t)c * CB * 1024);
    }
    k_finish<<<NB, 256, 0, stream>>>(part, c_f1W, f1_b, f2Wc, c_f2b, d_out, flags);
}